// Round 1
// baseline (561.257 us; speedup 1.0000x reference)
//
#include <hip/hip_runtime.h>
#include <hip/hip_bf16.h>

// Problem: CASSBlock — LN + direction-select + (fc1 -> dwconv3 -> gelu -> fc2) on the
// selected scan order, + residual. B=32 H=W=64 C=192 DIN=384 L=4096.
//
// Key insight: reference computes all 4 direction branches but selects one per batch.
// We compute dir_idx first, then run the seq-block only on the selected layout.
// "unscan" is a plain reshape => entire seq block is identity in flat index space;
// only the INPUT gather depends on direction:
//   d=0: src = l
//   d=1,2: src = (l&63)*64 + (l>>6)
//   d=3:   src = (l&63)*64 + 63 - (l>>6)
//
// ws layout (bytes):
//   xn   bf16 [32*4096*192]   @ 0          (50,331,648)
//   hbuf bf16 [32*4096*384]   @ 50331648   (100,663,296)
//   g    f32  [32*4096]       @ 150994944  (524,288)
//   w1s  bf16 [73728]         @ 151519232  (fragment-ordered fc1_w)
//   w2s  bf16 [73728]         @ 151666688  (fragment-ordered fc2_w)
//   dir  int  [32]            @ 151814144
// total ~151.8 MB

typedef __bf16 bf16x8 __attribute__((ext_vector_type(8)));
typedef float f32x4 __attribute__((ext_vector_type(4)));
typedef __hip_bfloat16 hb;

#define XN_OFF   0
#define HB_OFF   50331648
#define G_OFF    150994944
#define W1S_OFF  151519232
#define W2S_OFF  151666688
#define DIR_OFF  151814144

// ---------------- Kernel 1: LayerNorm + channel-mean g ----------------
// one wave per pixel (C=192 = 64 lanes * 3), 4 pixels per block
__global__ __launch_bounds__(256) void ln_kernel(
    const float* __restrict__ x, const float* __restrict__ nw,
    const float* __restrict__ nb, hb* __restrict__ xn, float* __restrict__ g) {
  int lane = threadIdx.x & 63;
  long pix = ((long)blockIdx.x << 2) + (threadIdx.x >> 6);
  const float* xp = x + pix * 192 + lane * 3;
  float v0 = xp[0], v1 = xp[1], v2 = xp[2];
  float s1 = v0 + v1 + v2;
  float s2 = v0 * v0 + v1 * v1 + v2 * v2;
  #pragma unroll
  for (int off = 32; off; off >>= 1) {
    s1 += __shfl_xor(s1, off);
    s2 += __shfl_xor(s2, off);
  }
  float mu = s1 * (1.f / 192.f);
  float var = s2 * (1.f / 192.f) - mu * mu;
  float rstd = rsqrtf(var + 1e-5f);
  int c = lane * 3;
  float y0 = (v0 - mu) * rstd * nw[c + 0] + nb[c + 0];
  float y1 = (v1 - mu) * rstd * nw[c + 1] + nb[c + 1];
  float y2 = (v2 - mu) * rstd * nw[c + 2] + nb[c + 2];
  float gs = y0 + y1 + y2;
  #pragma unroll
  for (int off = 32; off; off >>= 1) gs += __shfl_xor(gs, off);
  hb* xo = xn + pix * 192 + c;
  xo[0] = __float2bfloat16(y0);
  xo[1] = __float2bfloat16(y1);
  xo[2] = __float2bfloat16(y2);
  if (lane == 0) g[pix] = gs * (1.f / 192.f);
}

// ---------------- Kernel 2: direction selector ----------------
// one block per batch. reflect-pad gradient means -> scores -> MLP -> argmax
__global__ __launch_bounds__(256) void sel_kernel(
    const float* __restrict__ g, const float* __restrict__ w1,
    const float* __restrict__ b1, const float* __restrict__ w2,
    const float* __restrict__ b2, int* __restrict__ dir) {
  __shared__ float gt[64][65];
  __shared__ float red[8];
  int b = blockIdx.x, t = threadIdx.x;
  const float* gb = g + (long)b * 4096;
  for (int i = t; i < 4096; i += 256) gt[i >> 6][i & 63] = gb[i];
  __syncthreads();
  float ah = 0.f, av = 0.f;
  // sh: horizontal grads |g[r][j+1]-g[r][j-1]|, j=1..62; rows 1 and 62 counted twice
  for (int i = t; i < 3968; i += 256) {
    int r = i / 62, j = i - r * 62 + 1;
    float d = fabsf(gt[r][j + 1] - gt[r][j - 1]);
    if (r == 1 || r == 62) d *= 2.f;
    ah += d;
  }
  // sv: vertical grads |g[i+1][c]-g[i-1][c]|, i=1..62; cols 1 and 62 counted twice
  for (int i = t; i < 3968; i += 256) {
    int r = (i >> 6) + 1, c = i & 63;
    float d = fabsf(gt[r + 1][c] - gt[r - 1][c]);
    if (c == 1 || c == 62) d *= 2.f;
    av += d;
  }
  #pragma unroll
  for (int off = 32; off; off >>= 1) {
    ah += __shfl_xor(ah, off);
    av += __shfl_xor(av, off);
  }
  if ((t & 63) == 0) { red[(t >> 6) * 2] = ah; red[(t >> 6) * 2 + 1] = av; }
  __syncthreads();
  if (t == 0) {
    float sh = 0.f, sv = 0.f;
    for (int w = 0; w < 4; w++) { sh += red[w * 2]; sv += red[w * 2 + 1]; }
    sh *= (1.f / 4224.f);  // (H+2)*W = 66*64
    sv *= (1.f / 4224.f);  // H*(W+2) = 64*66
    float sc[4] = {sh, sv, 0.5f * (sh + sv), fabsf(sh - sv)};
    float hid[16];
    #pragma unroll
    for (int i = 0; i < 16; i++) {
      float a = b1[i];
      for (int k = 0; k < 4; k++) a += sc[k] * w1[i * 4 + k];
      hid[i] = fmaxf(a, 0.f);
    }
    float best = -1e30f; int bi = 0;
    for (int j = 0; j < 4; j++) {
      float a = b2[j];
      for (int i = 0; i < 16; i++) a += hid[i] * w2[j * 16 + i];
      if (a > best) { best = a; bi = j; }
    }
    dir[b] = bi;
  }
}

// ---------------- Kernel 3: weight shuffle to MFMA fragment order ----------------
// b_frag element j for fragment (nt,ks), lane: W[n= nt*16+(lane&15)][k= ks*32+(lane>>4)*8+j]
// stored at out[f*512 + lane*8 + j], f = nt*KS + ks  => B-loads are coalesced 1KB blocks
__global__ __launch_bounds__(256) void wshuf_kernel(
    const float* __restrict__ fc1_w, const float* __restrict__ fc2_w,
    hb* __restrict__ w1s, hb* __restrict__ w2s) {
  int idx = blockIdx.x * 256 + threadIdx.x;
  const float* w; hb* o; int K, KS, li;
  if (idx < 73728) { w = fc1_w; o = w1s; K = 192; KS = 6;  li = idx; }
  else             { w = fc2_w; o = w2s; K = 384; KS = 12; li = idx - 73728; }
  int j = li & 7, lane = (li >> 3) & 63, f = li >> 9;
  int ks = f % KS, nt = f / KS;
  int n = nt * 16 + (lane & 15);
  int k = ks * 32 + ((lane >> 4) << 3) + j;
  o[li] = __float2bfloat16(w[n * K + k]);
}

// ---------------- Kernel 4: GEMM1  h = gather(xn) @ fc1_w^T + b ----------------
// block: (mt, b). 64 rows x 384 cols. 4 waves, wave w owns rows [w*16, w*16+16)
__global__ __launch_bounds__(256) void gemm1_kernel(
    const hb* __restrict__ xn, const hb* __restrict__ w1s,
    const float* __restrict__ fc1_b, const int* __restrict__ dirp,
    hb* __restrict__ hbuf) {
  __shared__ hb sA[64 * 200];  // stride 200 bf16 = 400B: even bank spread
  int b = blockIdx.y, mt = blockIdx.x;
  int dir = dirp[b];
  int l0 = mt << 6;
  int t = threadIdx.x;
  {  // stage 64 rows of the direction-gathered sequence
    int r = t >> 2, part = t & 3;
    int l = l0 + r;
    int src;
    if (dir == 0)      src = l;
    else if (dir == 3) src = ((l & 63) << 6) + 63 - (l >> 6);
    else               src = ((l & 63) << 6) + (l >> 6);
    const int4* s4 = (const int4*)(xn + ((long)b * 4096 + src) * 192 + part * 48);
    int4* d4 = (int4*)(sA + r * 200 + part * 48);
    #pragma unroll
    for (int i = 0; i < 6; i++) d4[i] = s4[i];
  }
  __syncthreads();
  int wave = t >> 6, lane = t & 63;
  int m16 = lane & 15, q = lane >> 4;
  bf16x8 af[6];
  const hb* arow = sA + (wave * 16 + m16) * 200 + q * 8;
  #pragma unroll
  for (int ks = 0; ks < 6; ks++) af[ks] = *(const bf16x8*)(arow + ks * 32);
  const bf16x8* bbase = (const bf16x8*)w1s;
  long hb_base = ((long)b * 4096 + l0 + wave * 16 + q * 4) * 384;
  for (int nt = 0; nt < 24; nt++) {
    f32x4 acc = {0.f, 0.f, 0.f, 0.f};
    #pragma unroll
    for (int ks = 0; ks < 6; ks++) {
      acc = __builtin_amdgcn_mfma_f32_16x16x32_bf16(af[ks], bbase[(nt * 6 + ks) * 64 + lane], acc, 0, 0, 0);
    }
    int n = nt * 16 + m16;
    float bias = fc1_b[n];
    #pragma unroll
    for (int r = 0; r < 4; r++)
      hbuf[hb_base + (long)r * 384 + n] = __float2bfloat16(acc[r] + bias);
  }
}

// ---------------- Kernel 5: conv3+gelu then GEMM2 + residual ----------------
__global__ __launch_bounds__(256) void gemm2_kernel(
    const hb* __restrict__ hbuf, const hb* __restrict__ w2s,
    const float* __restrict__ fc2_b, const float* __restrict__ conv_w,
    const float* __restrict__ conv_b, const float* __restrict__ x,
    float* __restrict__ out) {
  __shared__ hb sAa[64 * 392];  // stride 392 bf16 = 784B
  int b = blockIdx.y, mt = blockIdx.x;
  int l0 = mt << 6;
  int t = threadIdx.x;
  const hb* hb_b = hbuf + (long)b * 4096 * 384;
  for (int ii = 0; ii < 96; ii++) {  // 64*384 / 256
    int i = t + ii * 256;
    int r = i / 384, d = i - r * 384;
    int l = l0 + r;
    float hm = (l > 0)    ? __bfloat162float(hb_b[(long)(l - 1) * 384 + d]) : 0.f;
    float hc =              __bfloat162float(hb_b[(long)l * 384 + d]);
    float hp = (l < 4095) ? __bfloat162float(hb_b[(long)(l + 1) * 384 + d]) : 0.f;
    float v = hm * conv_w[d * 3] + hc * conv_w[d * 3 + 1] + hp * conv_w[d * 3 + 2] + conv_b[d];
    v = 0.5f * v * (1.f + erff(v * 0.70710678118654752f));  // exact gelu
    sAa[r * 392 + d] = __float2bfloat16(v);
  }
  __syncthreads();
  int wave = t >> 6, lane = t & 63;
  int m16 = lane & 15, q = lane >> 4;
  bf16x8 af[12];
  const hb* arow = sAa + (wave * 16 + m16) * 392 + q * 8;
  #pragma unroll
  for (int ks = 0; ks < 12; ks++) af[ks] = *(const bf16x8*)(arow + ks * 32);
  const bf16x8* bbase = (const bf16x8*)w2s;
  long obase = ((long)b * 4096 + l0 + wave * 16 + q * 4) * 192;
  for (int nt = 0; nt < 12; nt++) {
    f32x4 acc = {0.f, 0.f, 0.f, 0.f};
    #pragma unroll
    for (int ks = 0; ks < 12; ks++) {
      acc = __builtin_amdgcn_mfma_f32_16x16x32_bf16(af[ks], bbase[(nt * 12 + ks) * 64 + lane], acc, 0, 0, 0);
    }
    int c = nt * 16 + m16;
    float bias = fc2_b[c];
    #pragma unroll
    for (int r = 0; r < 4; r++) {
      long idx = obase + (long)r * 192 + c;
      out[idx] = x[idx] + acc[r] + bias;
    }
  }
}

extern "C" void kernel_launch(void* const* d_in, const int* in_sizes, int n_in,
                              void* d_out, int out_size, void* d_ws, size_t ws_size,
                              hipStream_t stream) {
  const float* x      = (const float*)d_in[0];
  const float* norm_w = (const float*)d_in[1];
  const float* norm_b = (const float*)d_in[2];
  const float* sel_w1 = (const float*)d_in[3];
  const float* sel_b1 = (const float*)d_in[4];
  const float* sel_w2 = (const float*)d_in[5];
  const float* sel_b2 = (const float*)d_in[6];
  const float* fc1_w  = (const float*)d_in[7];
  const float* fc1_b  = (const float*)d_in[8];
  const float* conv_w = (const float*)d_in[9];
  const float* conv_b = (const float*)d_in[10];
  const float* fc2_w  = (const float*)d_in[11];
  const float* fc2_b  = (const float*)d_in[12];
  float* out = (float*)d_out;
  char* ws = (char*)d_ws;

  hb* xn    = (hb*)(ws + XN_OFF);
  hb* hbuf  = (hb*)(ws + HB_OFF);
  float* g  = (float*)(ws + G_OFF);
  hb* w1s   = (hb*)(ws + W1S_OFF);
  hb* w2s   = (hb*)(ws + W2S_OFF);
  int* dir  = (int*)(ws + DIR_OFF);

  ln_kernel<<<32768, 256, 0, stream>>>(x, norm_w, norm_b, xn, g);
  sel_kernel<<<32, 256, 0, stream>>>(g, sel_w1, sel_b1, sel_w2, sel_b2, dir);
  wshuf_kernel<<<576, 256, 0, stream>>>(fc1_w, fc2_w, w1s, w2s);
  dim3 gg(64, 32);
  gemm1_kernel<<<gg, 256, 0, stream>>>(xn, w1s, fc1_b, dir, hbuf);
  gemm2_kernel<<<gg, 256, 0, stream>>>(hbuf, w2s, fc2_b, conv_w, conv_b, x, out);
}

// Round 2
// 421.835 us; speedup vs baseline: 1.3305x; 1.3305x over previous
//
#include <hip/hip_runtime.h>
#include <hip/hip_bf16.h>
#include <math.h>

// CASSBlock fused: LN -> dir-select -> [gather -> fc1 -> dwconv3 -> gelu(exact) -> fc2] -> +x
// B=32 H=W=64 C=192 DIN=384 L=4096.
// Round 2: single fused seq-block kernel (no hbuf round-trip). Conv halo handled by
// computing a 66-row h-tile per 64-row output tile (5 MFMA M-tiles). N-split into two
// passes so the h LDS tile is half-width; fc2 accumulators persist across passes.
//
// ws layout (bytes):
//   xn   bf16 [32*4096*192]   @ 0          (50,331,648)
//   g    f32  [32*4096]       @ 50331648   (524,288)
//   w1s  bf16 [73728]         @ 50855936   (fragment-ordered fc1_w)
//   w2s  bf16 [73728]         @ 51003392   (fragment-ordered fc2_w)
//   dir  int  [32]            @ 51150848

typedef __bf16 bf16x8 __attribute__((ext_vector_type(8)));
typedef float f32x4 __attribute__((ext_vector_type(4)));
typedef __hip_bfloat16 hb;

#define XN_OFF   0
#define G_OFF    50331648
#define W1S_OFF  50855936
#define W2S_OFF  51003392
#define DIR_OFF  51150848

// ---------------- Kernel 1: LayerNorm + channel-mean g ----------------
__global__ __launch_bounds__(256) void ln_kernel(
    const float* __restrict__ x, const float* __restrict__ nw,
    const float* __restrict__ nb, hb* __restrict__ xn, float* __restrict__ g) {
  int lane = threadIdx.x & 63;
  long pix = ((long)blockIdx.x << 2) + (threadIdx.x >> 6);
  const float* xp = x + pix * 192 + lane * 3;
  float v0 = xp[0], v1 = xp[1], v2 = xp[2];
  float s1 = v0 + v1 + v2;
  float s2 = v0 * v0 + v1 * v1 + v2 * v2;
  #pragma unroll
  for (int off = 32; off; off >>= 1) {
    s1 += __shfl_xor(s1, off);
    s2 += __shfl_xor(s2, off);
  }
  float mu = s1 * (1.f / 192.f);
  float var = s2 * (1.f / 192.f) - mu * mu;
  float rstd = rsqrtf(var + 1e-5f);
  int c = lane * 3;
  float y0 = (v0 - mu) * rstd * nw[c + 0] + nb[c + 0];
  float y1 = (v1 - mu) * rstd * nw[c + 1] + nb[c + 1];
  float y2 = (v2 - mu) * rstd * nw[c + 2] + nb[c + 2];
  float gs = y0 + y1 + y2;
  #pragma unroll
  for (int off = 32; off; off >>= 1) gs += __shfl_xor(gs, off);
  hb* xo = xn + pix * 192 + c;
  xo[0] = __float2bfloat16(y0);
  xo[1] = __float2bfloat16(y1);
  xo[2] = __float2bfloat16(y2);
  if (lane == 0) g[pix] = gs * (1.f / 192.f);
}

// ---------------- Kernel 2: direction selector ----------------
__global__ __launch_bounds__(256) void sel_kernel(
    const float* __restrict__ g, const float* __restrict__ w1,
    const float* __restrict__ b1, const float* __restrict__ w2,
    const float* __restrict__ b2, int* __restrict__ dir) {
  __shared__ float gt[64][65];
  __shared__ float red[8];
  int b = blockIdx.x, t = threadIdx.x;
  const float* gb = g + (long)b * 4096;
  for (int i = t; i < 4096; i += 256) gt[i >> 6][i & 63] = gb[i];
  __syncthreads();
  float ah = 0.f, av = 0.f;
  for (int i = t; i < 3968; i += 256) {
    int r = i / 62, j = i - r * 62 + 1;
    float d = fabsf(gt[r][j + 1] - gt[r][j - 1]);
    if (r == 1 || r == 62) d *= 2.f;
    ah += d;
  }
  for (int i = t; i < 3968; i += 256) {
    int r = (i >> 6) + 1, c = i & 63;
    float d = fabsf(gt[r + 1][c] - gt[r - 1][c]);
    if (c == 1 || c == 62) d *= 2.f;
    av += d;
  }
  #pragma unroll
  for (int off = 32; off; off >>= 1) {
    ah += __shfl_xor(ah, off);
    av += __shfl_xor(av, off);
  }
  if ((t & 63) == 0) { red[(t >> 6) * 2] = ah; red[(t >> 6) * 2 + 1] = av; }
  __syncthreads();
  if (t == 0) {
    float sh = 0.f, sv = 0.f;
    for (int w = 0; w < 4; w++) { sh += red[w * 2]; sv += red[w * 2 + 1]; }
    sh *= (1.f / 4224.f);
    sv *= (1.f / 4224.f);
    float sc[4] = {sh, sv, 0.5f * (sh + sv), fabsf(sh - sv)};
    float hid[16];
    #pragma unroll
    for (int i = 0; i < 16; i++) {
      float a = b1[i];
      for (int k = 0; k < 4; k++) a += sc[k] * w1[i * 4 + k];
      hid[i] = fmaxf(a, 0.f);
    }
    float best = -1e30f; int bi = 0;
    for (int j = 0; j < 4; j++) {
      float a = b2[j];
      for (int i = 0; i < 16; i++) a += hid[i] * w2[j * 16 + i];
      if (a > best) { best = a; bi = j; }
    }
    dir[b] = bi;
  }
}

// ---------------- Kernel 3: weight shuffle to MFMA fragment order ----------------
// frag f = nt*KS + ks; element j, lane: W[n=nt*16+(lane&15)][k=ks*32+(lane>>4)*8+j]
__global__ __launch_bounds__(256) void wshuf_kernel(
    const float* __restrict__ fc1_w, const float* __restrict__ fc2_w,
    hb* __restrict__ w1s, hb* __restrict__ w2s) {
  int idx = blockIdx.x * 256 + threadIdx.x;
  const float* w; hb* o; int K, KS, li;
  if (idx < 73728) { w = fc1_w; o = w1s; K = 192; KS = 6;  li = idx; }
  else             { w = fc2_w; o = w2s; K = 384; KS = 12; li = idx - 73728; }
  int j = li & 7, lane = (li >> 3) & 63, f = li >> 9;
  int ks = f % KS, nt = f / KS;
  int n = nt * 16 + (lane & 15);
  int k = ks * 32 + ((lane >> 4) << 3) + j;
  o[li] = __float2bfloat16(w[n * K + k]);
}

// ---------------- Kernel 4: fused seq block ----------------
// block = (mt, b): 64 output rows l0..l0+63. 66-row h tile (halo for conv).
// Two passes over n-halves of fc1 / k-halves of fc2.
#define SX_STRIDE 196
#define SH_STRIDE 196
__global__ __launch_bounds__(256) void fused_kernel(
    const hb* __restrict__ xn, const hb* __restrict__ w1s, const hb* __restrict__ w2s,
    const float* __restrict__ fc1_b, const float* __restrict__ fc2_b,
    const float* __restrict__ conv_w, const float* __restrict__ conv_b,
    const float* __restrict__ x, const int* __restrict__ dirp,
    float* __restrict__ out) {
  __shared__ hb sX[80 * SX_STRIDE];    // 66 real rows (+14 never-read but in-bounds)
  __shared__ hb sH[66 * SH_STRIDE];    // half-width h tile (192 cols)
  __shared__ float4 cvt[384];          // {w0,w1,w2,b} per d

  int b = blockIdx.y, mt = blockIdx.x;
  int dir = dirp[b];
  int l0 = mt << 6;
  int t = threadIdx.x;

  // stage conv coeffs
  for (int d = t; d < 384; d += 256)
    cvt[d] = make_float4(conv_w[d * 3], conv_w[d * 3 + 1], conv_w[d * 3 + 2], conv_b[d]);

  // stage gathered xn rows r=0..65  (l = l0-1+r), 4 threads per row
  {
    int r = t >> 2, part = t & 3;
    #pragma unroll
    for (int pass = 0; pass < 2; pass++) {
      int rr = r + pass * 64;
      if (rr < 66) {
        int l = l0 - 1 + rr;
        int lc = min(max(l, 0), 4095);  // clamp; garbage halo rows are masked at conv
        int src;
        if (dir == 0)      src = lc;
        else if (dir == 3) src = ((lc & 63) << 6) + 63 - (lc >> 6);
        else               src = ((lc & 63) << 6) + (lc >> 6);
        const int4* s4 = (const int4*)(xn + ((long)b * 4096 + src) * 192 + part * 48);
        int4* d4 = (int4*)(sX + rr * SX_STRIDE + part * 48);
        #pragma unroll
        for (int i = 0; i < 6; i++) d4[i] = s4[i];
      }
    }
  }
  __syncthreads();

  int wave = t >> 6, lane = t & 63;
  int m16 = lane & 15, q = lane >> 4;
  const bf16x8* b1base = (const bf16x8*)w1s;
  const bf16x8* b2base = (const bf16x8*)w2s;

  f32x4 acc2[12];
  #pragma unroll
  for (int i = 0; i < 12; i++) acc2[i] = (f32x4){0.f, 0.f, 0.f, 0.f};

  int m_local = wave * 16 + m16;  // gemm2 output row (0..63)
  bool hm_ok = (mt > 0) || (m_local > 0);
  bool hp_ok = (mt < 63) || (m_local < 63);

  for (int pass = 0; pass < 2; pass++) {
    // ---- fc1 half: n in [pass*192, pass*192+192), 5 M-tiles x 12 nt = 60 units
    int u0 = wave * 15;
    int tile = u0 / 12, ntl = u0 - tile * 12;
    int cur_tile = -1;
    bf16x8 af[6];
    for (int u = 0; u < 15; u++) {
      if (tile != cur_tile) {
        cur_tile = tile;
        const hb* arow = sX + (tile * 16 + m16) * SX_STRIDE + q * 8;
        #pragma unroll
        for (int ks = 0; ks < 6; ks++) af[ks] = *(const bf16x8*)(arow + ks * 32);
      }
      int nt = pass * 12 + ntl;
      f32x4 acc = {0.f, 0.f, 0.f, 0.f};
      #pragma unroll
      for (int ks = 0; ks < 6; ks++)
        acc = __builtin_amdgcn_mfma_f32_16x16x32_bf16(af[ks], b1base[(nt * 6 + ks) * 64 + lane], acc, 0, 0, 0);
      int n = nt * 16 + m16;
      float bias = fc1_b[n];
      int n_local = ntl * 16 + m16;
      #pragma unroll
      for (int r = 0; r < 4; r++) {
        int grow = tile * 16 + q * 4 + r;
        if (grow < 66) sH[grow * SH_STRIDE + n_local] = __float2bfloat16(acc[r] + bias);
      }
      ntl++;
      if (ntl == 12) { ntl = 0; tile++; }
    }
    __syncthreads();

    // ---- conv + gelu into A-fragments (registers), then fc2 accumulate
    bf16x8 af2[6];
    const hb* hrow = sH + m_local * SH_STRIDE + q * 8;
    #pragma unroll
    for (int ksl = 0; ksl < 6; ksl++) {
      bf16x8 vm = *(const bf16x8*)(hrow + ksl * 32);
      bf16x8 vc = *(const bf16x8*)(hrow + SH_STRIDE + ksl * 32);
      bf16x8 vp = *(const bf16x8*)(hrow + 2 * SH_STRIDE + ksl * 32);
      int d0 = pass * 192 + ksl * 32 + q * 8;
      bf16x8 o;
      #pragma unroll
      for (int j = 0; j < 8; j++) {
        float4 cw = cvt[d0 + j];
        float hm = hm_ok ? (float)vm[j] : 0.f;
        float hc = (float)vc[j];
        float hp = hp_ok ? (float)vp[j] : 0.f;
        float v = hm * cw.x + hc * cw.y + hp * cw.z + cw.w;
        v = 0.5f * v * (1.f + erff(v * 0.70710678118654752f));
        o[j] = (__bf16)v;
      }
      af2[ksl] = o;
    }
    #pragma unroll
    for (int nt = 0; nt < 12; nt++) {
      #pragma unroll
      for (int ksl = 0; ksl < 6; ksl++) {
        int ksg = pass * 6 + ksl;
        acc2[nt] = __builtin_amdgcn_mfma_f32_16x16x32_bf16(af2[ksl], b2base[(nt * 12 + ksg) * 64 + lane], acc2[nt], 0, 0, 0);
      }
    }
    __syncthreads();  // before fc1 of next pass overwrites sH
  }

  // ---- epilogue: out = x + acc2 + fc2_b
  long obase = ((long)b * 4096 + l0 + wave * 16 + q * 4) * 192;
  #pragma unroll
  for (int nt = 0; nt < 12; nt++) {
    int c = nt * 16 + m16;
    float bias = fc2_b[c];
    #pragma unroll
    for (int r = 0; r < 4; r++) {
      long idx = obase + (long)r * 192 + c;
      out[idx] = x[idx] + acc2[nt][r] + bias;
    }
  }
}

extern "C" void kernel_launch(void* const* d_in, const int* in_sizes, int n_in,
                              void* d_out, int out_size, void* d_ws, size_t ws_size,
                              hipStream_t stream) {
  const float* x      = (const float*)d_in[0];
  const float* norm_w = (const float*)d_in[1];
  const float* norm_b = (const float*)d_in[2];
  const float* sel_w1 = (const float*)d_in[3];
  const float* sel_b1 = (const float*)d_in[4];
  const float* sel_w2 = (const float*)d_in[5];
  const float* sel_b2 = (const float*)d_in[6];
  const float* fc1_w  = (const float*)d_in[7];
  const float* fc1_b  = (const float*)d_in[8];
  const float* conv_w = (const float*)d_in[9];
  const float* conv_b = (const float*)d_in[10];
  const float* fc2_w  = (const float*)d_in[11];
  const float* fc2_b  = (const float*)d_in[12];
  float* out = (float*)d_out;
  char* ws = (char*)d_ws;

  hb* xn    = (hb*)(ws + XN_OFF);
  float* g  = (float*)(ws + G_OFF);
  hb* w1s   = (hb*)(ws + W1S_OFF);
  hb* w2s   = (hb*)(ws + W2S_OFF);
  int* dir  = (int*)(ws + DIR_OFF);

  ln_kernel<<<32768, 256, 0, stream>>>(x, norm_w, norm_b, xn, g);
  sel_kernel<<<32, 256, 0, stream>>>(g, sel_w1, sel_b1, sel_w2, sel_b2, dir);
  wshuf_kernel<<<576, 256, 0, stream>>>(fc1_w, fc2_w, w1s, w2s);
  dim3 gg(64, 32);
  fused_kernel<<<gg, 256, 0, stream>>>(xn, w1s, w2s, fc1_b, fc2_b,
                                       conv_w, conv_b, x, dir, out);
}